// Round 8
// baseline (43.062 us; speedup 1.0000x reference)
//
#include <hip/hip_runtime.h>

// B=8192, D=1024, C=90, K=16.
// Three kernels, deterministic, no atomics, no LDS in the hot path:
//  (1) bin_labels: ballot-binning of sample ids by class (90 blocks) -> ws.
//  (2) dots_flat: FLAT PADDED work decomposition. Each class's list is
//      padded to a multiple of 16; block b owns flat positions [16b,16b+16),
//      which lie inside exactly ONE class. Each block redundantly computes
//      the 90-class padded prefix from counts[] via a wave shuffle-scan
//      (~30 ops, no LDS, no barriers), then its 4 INDEPENDENT waves each
//      process 4 samples full-D: 16 upfront x float4 loads (deep MLP),
//      16x4 center loads (L2-resident), 1024 FMAs, DPP/shuffle REDUCE16,
//      in-wave epilogue, one partial per wave. Uniform work per live block,
//      dead blocks exit in a compact tail. Zero __syncthreads.
//  (3) reduce_final: 2400 partials -> mean.

#define B_SAMP  8192
#define D_DIM   1024
#define K_SUB   16
#define C_CLS   90
#define LISTCAP 192             // per-class capacity (mean 91, 10.6 sigma)
#define F4_ROW  256             // float4 per D=1024 row
#define MAXBLK  600             // >= ceil((8192 + 90*15)/16) = 597
#define NPART   (MAXBLK * 4)

// ws layout (bytes)
#define OFF_COUNTS 0            // 90 ints
#define OFF_LISTS  4096         // 90*192 ints
#define OFF_PART   (1u << 20)   // NPART floats

template <int CTRL>
__device__ __forceinline__ float dpp_qperm(float v) {
    return __int_as_float(__builtin_amdgcn_update_dpp(
        0, __float_as_int(v), CTRL, 0xF, 0xF, true));
}

__device__ __forceinline__ float dot16(float4 c0, float4 c1, float4 c2, float4 c3,
                                       float4 y0, float4 y1, float4 y2, float4 y3)
{
    float t = 0.0f;
    t = fmaf(y0.x, c0.x, t); t = fmaf(y0.y, c0.y, t);
    t = fmaf(y0.z, c0.z, t); t = fmaf(y0.w, c0.w, t);
    t = fmaf(y1.x, c1.x, t); t = fmaf(y1.y, c1.y, t);
    t = fmaf(y1.z, c1.z, t); t = fmaf(y1.w, c1.w, t);
    t = fmaf(y2.x, c2.x, t); t = fmaf(y2.y, c2.y, t);
    t = fmaf(y2.z, c2.z, t); t = fmaf(y2.w, c2.w, t);
    t = fmaf(y3.x, c3.x, t); t = fmaf(y3.y, c3.y, t);
    t = fmaf(y3.z, c3.z, t); t = fmaf(y3.w, c3.w, t);
    return t;
}

// 16-lane-group epilogue: lane holds d for k=kk within its 16-group.
// Returns the per-sample loss replicated across the group. (Verified R6/R7.)
__device__ __forceinline__ float sample_loss16(float r, int kk)
{
    const float d = 1.0f - r;
    float S = d;
    S += __shfl_xor(S, 1, 64);
    S += __shfl_xor(S, 2, 64);
    S += __shfl_xor(S, 4, 64);
    S += __shfl_xor(S, 8, 64);
    float dmin = d;
    dmin = fminf(dmin, __shfl_xor(dmin, 1, 64));
    dmin = fminf(dmin, __shfl_xor(dmin, 2, 64));
    dmin = fminf(dmin, __shfl_xor(dmin, 4, 64));
    dmin = fminf(dmin, __shfl_xor(dmin, 8, 64));
    int cand = (d == dmin) ? kk : 99;      // first-min == jnp.argmin
    cand = min(cand, __shfl_xor(cand, 1, 64));
    cand = min(cand, __shfl_xor(cand, 2, 64));
    cand = min(cand, __shfl_xor(cand, 4, 64));
    cand = min(cand, __shfl_xor(cand, 8, 64));
    const float inv = 1.0f / S;
    float t = (kk == cand) ? (d * d * inv)            // term1
                           : ((1.0f - d * inv) * d);  // term2
    t += __shfl_xor(t, 1, 64);
    t += __shfl_xor(t, 2, 64);
    t += __shfl_xor(t, 4, 64);
    t += __shfl_xor(t, 8, 64);
    return t;
}

// ---------------- Kernel 1: bin labels by class (90 blocks) ----------------
__global__ __launch_bounds__(256) void bin_labels(
    const int* __restrict__ labels,
    int*       __restrict__ counts,
    int*       __restrict__ lists)
{
    const int c    = blockIdx.x;
    const int tid  = threadIdx.x;
    const int wave = tid >> 6;
    const int lane = tid & 63;
    __shared__ int wcnt[4];

    const int4* lv = reinterpret_cast<const int4*>(labels);

    int4 seg[8];
    int cnt = 0;
#pragma unroll
    for (int it = 0; it < 8; ++it) {
        seg[it] = lv[wave * 512 + it * 64 + lane];
        cnt += (seg[it].x == c) + (seg[it].y == c) + (seg[it].z == c) + (seg[it].w == c);
    }
#pragma unroll
    for (int off = 32; off > 0; off >>= 1) cnt += __shfl_xor(cnt, off, 64);
    if (lane == 0) wcnt[wave] = cnt;
    __syncthreads();

    int base = 0;
    for (int w = 0; w < wave; ++w) base += wcnt[w];
    const int total = wcnt[0] + wcnt[1] + wcnt[2] + wcnt[3];

#pragma unroll
    for (int it = 0; it < 8; ++it) {
        const int idx0 = (wave * 512 + it * 64 + lane) * 4;
        const int ls[4] = { seg[it].x, seg[it].y, seg[it].z, seg[it].w };
#pragma unroll
        for (int u = 0; u < 4; ++u) {
            const bool hit = (ls[u] == c);
            const unsigned long long m = __ballot(hit);
            if (hit) {
                const int p = base + (int)__popcll(m & ((1ull << lane) - 1ull));
                if (p < LISTCAP) lists[c * LISTCAP + p] = idx0 + u;
            }
            base += (int)__popcll(m);
        }
    }
    if (tid == 0) counts[c] = (total <= LISTCAP) ? total : LISTCAP;
}

// ---------------- Kernel 2: flat-padded dots + in-wave loss ----------------
__global__ __launch_bounds__(256) void dots_flat(
    const float* __restrict__ x,
    const float* __restrict__ centers,
    const int*   __restrict__ counts,
    const int*   __restrict__ lists,
    float*       __restrict__ partials)
{
    const int b    = blockIdx.x;
    const int tid  = threadIdx.x;
    const int wv   = tid >> 6;
    const int lane = tid & 63;
    const int pos  = b * 16;           // flat padded position of this block

    // ---- per-wave padded-prefix scan over 90 class counts (no LDS) ----
    const int c1i = 64 + lane;
    const int n0 = (lane < C_CLS) ? counts[lane] : 0;
    const int n1 = (c1i  < C_CLS) ? counts[c1i]  : 0;
    const int p0 = (n0 + 15) & ~15;
    const int p1 = (n1 + 15) & ~15;
    int s0 = p0, s1 = p1;
#pragma unroll
    for (int off = 1; off < 64; off <<= 1) {
        const int t = __shfl_up(s0, off, 64);
        if (lane >= off) s0 += t;
    }
    const int tot0 = __shfl(s0, 63, 64);
#pragma unroll
    for (int off = 1; off < 64; off <<= 1) {
        const int t = __shfl_up(s1, off, 64);
        if (lane >= off) s1 += t;
    }
    s1 += tot0;
    const int ptotal = __shfl(s1, 63, 64);

    if (pos >= ptotal) {                       // compact dead tail
        if (lane == 0) partials[b * 4 + wv] = 0.0f;
        return;
    }

    const int e0 = s0 - p0, e1 = s1 - p1;      // exclusive padded starts
    const unsigned long long m0 = __ballot(p0 > 0 && pos >= e0 && pos < e0 + p0);
    const unsigned long long m1 = __ballot(p1 > 0 && pos >= e1 && pos < e1 + p1);
    int cls, pstart;
    if (m0) { const int l = (int)__ffsll(m0) - 1; cls = l;      pstart = __shfl(e0, l, 64); }
    else    { const int l = (int)__ffsll(m1) - 1; cls = 64 + l; pstart = __shfl(e1, l, 64); }
    const int cntc = (cls < 64) ? __shfl(n0, cls, 64) : __shfl(n1, cls - 64, 64);

    // ---- this wave's 4 samples ----
    const int j0 = pos - pstart + wv * 4;      // list offset, multiple of 4
    const int4 grp = *reinterpret_cast<const int4*>(lists + cls * LISTCAP + j0);
    const int idsafe = lists[cls * LISTCAP];   // always valid (cntc >= 1 here)
    int id[4];
    id[0] = (j0 + 0 < cntc) ? grp.x : idsafe;
    id[1] = (j0 + 1 < cntc) ? grp.y : idsafe;
    id[2] = (j0 + 2 < cntc) ? grp.z : idsafe;
    id[3] = (j0 + 3 < cntc) ? grp.w : idsafe;

    // ---- load 4 x rows (16 independent float4 HBM loads, issued upfront) ----
    const float4* xv = reinterpret_cast<const float4*>(x);
    float4 xr0[4], xr1[4], xr2[4], xr3[4];
#pragma unroll
    for (int q = 0; q < 4; ++q) {
        xr0[q] = xv[(size_t)id[0] * F4_ROW + q * 64 + lane];
        xr1[q] = xv[(size_t)id[1] * F4_ROW + q * 64 + lane];
        xr2[q] = xv[(size_t)id[2] * F4_ROW + q * 64 + lane];
        xr3[q] = xv[(size_t)id[3] * F4_ROW + q * 64 + lane];
    }

    // ---- 16 sub-center dots, full D in one pass (centers from L2) ----
    const float4* cbp = reinterpret_cast<const float4*>(centers)
                      + (size_t)cls * (K_SUB * F4_ROW);
    float a0[K_SUB], a1[K_SUB], a2[K_SUB], a3[K_SUB];
#pragma unroll 4
    for (int k = 0; k < K_SUB; ++k) {
        const float4 q0 = cbp[k * F4_ROW + lane];
        const float4 q1 = cbp[k * F4_ROW + 64 + lane];
        const float4 q2 = cbp[k * F4_ROW + 128 + lane];
        const float4 q3 = cbp[k * F4_ROW + 192 + lane];
        a0[k] = dot16(q0, q1, q2, q3, xr0[0], xr0[1], xr0[2], xr0[3]);
        a1[k] = dot16(q0, q1, q2, q3, xr1[0], xr1[1], xr1[2], xr1[3]);
        a2[k] = dot16(q0, q1, q2, q3, xr2[0], xr2[1], xr2[2], xr2[3]);
        a3[k] = dot16(q0, q1, q2, q3, xr3[0], xr3[1], xr3[2], xr3[3]);
    }

    // ---- value-halving reduction (xor1/2 on VALU via DPP, rest shuffles) ----
    const bool b0 = (lane & 1) != 0;
    const bool b1 = (lane & 2) != 0;
    const bool b2 = (lane & 4) != 0;
    const bool b3 = (lane & 8) != 0;
    const int kmap = 8 * (lane & 1) + 4 * ((lane >> 1) & 1)
                   + 2 * ((lane >> 2) & 1) + ((lane >> 3) & 1);

#define REDUCE16(A, OUT)                                                      \
    {                                                                         \
        _Pragma("unroll")                                                     \
        for (int j = 0; j < 8; ++j) {                                         \
            const float send = b0 ? A[j] : A[j + 8];                          \
            const float recv = dpp_qperm<0xB1>(send);       /* xor 1 */       \
            A[j] = (b0 ? A[j + 8] : A[j]) + recv;                             \
        }                                                                     \
        _Pragma("unroll")                                                     \
        for (int j = 0; j < 4; ++j) {                                         \
            const float send = b1 ? A[j] : A[j + 4];                          \
            const float recv = dpp_qperm<0x4E>(send);       /* xor 2 */       \
            A[j] = (b1 ? A[j + 4] : A[j]) + recv;                             \
        }                                                                     \
        _Pragma("unroll")                                                     \
        for (int j = 0; j < 2; ++j) {                                         \
            const float send = b2 ? A[j] : A[j + 2];                          \
            const float recv = __shfl_xor(send, 4, 64);                       \
            A[j] = (b2 ? A[j + 2] : A[j]) + recv;                             \
        }                                                                     \
        {                                                                     \
            const float send = b3 ? A[0] : A[1];                              \
            const float recv = __shfl_xor(send, 8, 64);                       \
            A[0] = (b3 ? A[1] : A[0]) + recv;                                 \
        }                                                                     \
        A[0] += __shfl_xor(A[0], 16, 64);                                     \
        A[0] += __shfl_xor(A[0], 32, 64);                                     \
        OUT = A[0];                                                           \
    }

    float r0, r1, r2, r3;
    REDUCE16(a0, r0)
    REDUCE16(a1, r1)
    REDUCE16(a2, r2)
    REDUCE16(a3, r3)
#undef REDUCE16

    // ---- in-wave epilogue (losses replicated across lanes; gates uniform) ----
    const float l0 = sample_loss16(r0, kmap);
    const float l1 = sample_loss16(r1, kmap);
    const float l2 = sample_loss16(r2, kmap);
    const float l3 = sample_loss16(r3, kmap);
    float wl = 0.0f;
    if (j0 + 0 < cntc) wl += l0;
    if (j0 + 1 < cntc) wl += l1;
    if (j0 + 2 < cntc) wl += l2;
    if (j0 + 3 < cntc) wl += l3;

    if (lane == 0) partials[b * 4 + wv] = wl;
}

// ---------------- Kernel 3: final mean over NPART partials ----------------
__global__ __launch_bounds__(256) void reduce_final(
    const float* __restrict__ partials,
    float*       __restrict__ out)
{
    const int tid  = threadIdx.x;
    const int wave = tid >> 6;
    const int lane = tid & 63;
    float s = 0.0f;
    for (int i = tid; i < NPART; i += 256) s += partials[i];
#pragma unroll
    for (int off = 32; off > 0; off >>= 1) s += __shfl_xor(s, off, 64);
    __shared__ float w[4];
    if (lane == 0) w[wave] = s;
    __syncthreads();
    if (tid == 0)
        out[0] = (w[0] + w[1] + w[2] + w[3]) * (1.0f / (float)B_SAMP);
}

extern "C" void kernel_launch(void* const* d_in, const int* in_sizes, int n_in,
                              void* d_out, int out_size, void* d_ws, size_t ws_size,
                              hipStream_t stream)
{
    const float* x       = (const float*)d_in[0];
    const int*   labels  = (const int*)  d_in[1];
    const float* centers = (const float*)d_in[2];
    float*       out     = (float*)d_out;
    char*        ws      = (char*)d_ws;

    int*   counts = (int*)  (ws + OFF_COUNTS);
    int*   lists  = (int*)  (ws + OFF_LISTS);
    float* parts  = (float*)(ws + OFF_PART);

    bin_labels  <<<C_CLS,  256, 0, stream>>>(labels, counts, lists);
    dots_flat   <<<MAXBLK, 256, 0, stream>>>(x, centers, counts, lists, parts);
    reduce_final<<<1,      256, 0, stream>>>(parts, out);
}

// Round 9
// 25.004 us; speedup vs baseline: 1.7222x; 1.7222x over previous
//
#include <hip/hip_runtime.h>

// B=8192, D=1024, C=90, K=16.
// R9: latency-hiding-first design.
//  (1) bin_labels (proven): per-class sample lists + counts.
//  (2) quad_dots: wave = (4 same-class samples, D-half). Grid 8*192 blocks;
//      block b serves XCD group g=b%8 and only classes c==g (mod 8), so each
//      XCD's L2 holds just ~12 classes (768 KB) of centers -> centers stream
//      at L2 speed; x rows are read EXACTLY once (disjoint D-halves). The
//      (quad -> class,offset) map is a 16-lane register scan of counts[] --
//      no LDS, no barrier. Registers stay ~100: acc is reduced every 4 k's
//      (4x REDUCE16), x = 32 VGPR. One __syncthreads per block (combine the
//      two D-half waves + in-block epilogue). ~4100 live waves, 4/SIMD cap.
//  (3) reduce_final: 3072 partials -> mean.

#define B_SAMP  8192
#define D_DIM   1024
#define K_SUB   16
#define C_CLS   90
#define LISTCAP 192             // per-class capacity (mean 91, ~10 sigma)
#define F4_ROW  256             // float4 per D=1024 row
#define TSLOT   192             // block slots per XCD group (2 quads each)
#define NBLK    (8 * TSLOT)     // 1536
#define NPART   (NBLK * 2)

// ws layout (bytes)
#define OFF_COUNTS 0            // 90 ints
#define OFF_LISTS  4096         // 90*192 ints
#define OFF_PART   (1u << 20)   // NPART floats

template <int CTRL>
__device__ __forceinline__ float dpp_qperm(float v) {
    return __int_as_float(__builtin_amdgcn_update_dpp(
        0, __float_as_int(v), CTRL, 0xF, 0xF, true));
}

__device__ __forceinline__ float dot8(float4 q0, float4 q1, float4 y0, float4 y1)
{
    float t = 0.0f;
    t = fmaf(y0.x, q0.x, t); t = fmaf(y0.y, q0.y, t);
    t = fmaf(y0.z, q0.z, t); t = fmaf(y0.w, q0.w, t);
    t = fmaf(y1.x, q1.x, t); t = fmaf(y1.y, q1.y, t);
    t = fmaf(y1.z, q1.z, t); t = fmaf(y1.w, q1.w, t);
    return t;
}

// 16-lane-group epilogue: lane holds d for k=kk within its 16-group.
// Returns the per-sample loss replicated across the group. (Verified R6-R8.)
__device__ __forceinline__ float sample_loss16(float r, int kk)
{
    const float d = 1.0f - r;
    float S = d;
    S += __shfl_xor(S, 1, 64);
    S += __shfl_xor(S, 2, 64);
    S += __shfl_xor(S, 4, 64);
    S += __shfl_xor(S, 8, 64);
    float dmin = d;
    dmin = fminf(dmin, __shfl_xor(dmin, 1, 64));
    dmin = fminf(dmin, __shfl_xor(dmin, 2, 64));
    dmin = fminf(dmin, __shfl_xor(dmin, 4, 64));
    dmin = fminf(dmin, __shfl_xor(dmin, 8, 64));
    int cand = (d == dmin) ? kk : 99;      // first-min == jnp.argmin
    cand = min(cand, __shfl_xor(cand, 1, 64));
    cand = min(cand, __shfl_xor(cand, 2, 64));
    cand = min(cand, __shfl_xor(cand, 4, 64));
    cand = min(cand, __shfl_xor(cand, 8, 64));
    const float inv = 1.0f / S;
    float t = (kk == cand) ? (d * d * inv)            // term1
                           : ((1.0f - d * inv) * d);  // term2
    t += __shfl_xor(t, 1, 64);
    t += __shfl_xor(t, 2, 64);
    t += __shfl_xor(t, 4, 64);
    t += __shfl_xor(t, 8, 64);
    return t;
}

// ---------------- Kernel 1: bin labels by class (90 blocks) ----------------
__global__ __launch_bounds__(256) void bin_labels(
    const int* __restrict__ labels,
    int*       __restrict__ counts,
    int*       __restrict__ lists)
{
    const int c    = blockIdx.x;
    const int tid  = threadIdx.x;
    const int wave = tid >> 6;
    const int lane = tid & 63;
    __shared__ int wcnt[4];

    const int4* lv = reinterpret_cast<const int4*>(labels);

    int4 seg[8];
    int cnt = 0;
#pragma unroll
    for (int it = 0; it < 8; ++it) {
        seg[it] = lv[wave * 512 + it * 64 + lane];
        cnt += (seg[it].x == c) + (seg[it].y == c) + (seg[it].z == c) + (seg[it].w == c);
    }
#pragma unroll
    for (int off = 32; off > 0; off >>= 1) cnt += __shfl_xor(cnt, off, 64);
    if (lane == 0) wcnt[wave] = cnt;
    __syncthreads();

    int base = 0;
    for (int w = 0; w < wave; ++w) base += wcnt[w];
    const int total = wcnt[0] + wcnt[1] + wcnt[2] + wcnt[3];

#pragma unroll
    for (int it = 0; it < 8; ++it) {
        const int idx0 = (wave * 512 + it * 64 + lane) * 4;
        const int ls[4] = { seg[it].x, seg[it].y, seg[it].z, seg[it].w };
#pragma unroll
        for (int u = 0; u < 4; ++u) {
            const bool hit = (ls[u] == c);
            const unsigned long long m = __ballot(hit);
            if (hit) {
                const int p = base + (int)__popcll(m & ((1ull << lane) - 1ull));
                if (p < LISTCAP) lists[c * LISTCAP + p] = idx0 + u;
            }
            base += (int)__popcll(m);
        }
    }
    if (tid == 0) counts[c] = (total <= LISTCAP) ? total : LISTCAP;
}

// ---------------- Kernel 2: XCD-pinned quad dots + in-block loss ----------------
__global__ __launch_bounds__(256) void quad_dots(
    const float* __restrict__ x,
    const float* __restrict__ centers,
    const int*   __restrict__ counts,
    const int*   __restrict__ lists,
    float*       __restrict__ partials)
{
    const int b    = blockIdx.x;
    const int g    = b & 7;                 // XCD group: classes c == g (mod 8)
    const int t    = b >> 3;
    const int tid  = threadIdx.x;
    const int wv   = tid >> 6;
    const int lane = tid & 63;
    const int pair = wv >> 1;               // 0 or 1: which quad
    const int h    = wv & 1;                // D-half

    __shared__ float sdots[4][4][16];       // [wave][sample][k]
    __shared__ float sgate[2][4];           // [pair][sample]

    // ---- 16-lane register scan: quad j -> (class, offset) ----
    const int cl  = g + 8 * lane;                       // lane<12 relevant
    const int n_l = (lane < 12 && cl < C_CLS) ? counts[cl] : 0;
    const int q_l = (n_l + 3) >> 2;                     // quads in this class
    int inc = q_l;
#pragma unroll
    for (int off = 1; off < 16; off <<= 1) {
        const int v = __shfl_up(inc, off, 64);
        if (lane >= off) inc += v;
    }
    const int Qg  = __shfl(inc, 15, 64);                // total quads in group
    const int exc = inc - q_l;

    const int j = 2 * t + pair;                         // this pair's quad id

    if (2 * t >= Qg) {                                  // whole block dead
        if (tid < 2) partials[b * 2 + tid] = 0.0f;
        return;                                         // uniform, pre-barrier
    }

    const bool livepair = (j < Qg);                     // wave-uniform

    if (livepair) {
        const bool hit = (lane < 16) && (q_l > 0) && (j >= exc) && (j < inc);
        const unsigned long long m = __ballot(hit);
        const int ls   = (int)__ffsll(m) - 1;
        const int cls  = g + 8 * ls;
        const int qoff = j - __shfl(exc, ls, 64);
        const int cntc = __shfl(n_l, ls, 64);
        const int base = qoff * 4;                      // < cntc always

        const int4 grp = *reinterpret_cast<const int4*>(lists + cls * LISTCAP + base);
        int id[4];
        id[0] = grp.x;
        id[1] = (base + 1 < cntc) ? grp.y : grp.x;
        id[2] = (base + 2 < cntc) ? grp.z : grp.x;
        id[3] = (base + 3 < cntc) ? grp.w : grp.x;

        // x rows: this wave's D-half only (disjoint across the pair) -> x
        // is fetched exactly once per row across the whole grid.
        const float4* xv = reinterpret_cast<const float4*>(x);
        float4 xr[4][2];
#pragma unroll
        for (int s = 0; s < 4; ++s) {
            const size_t xo = (size_t)id[s] * F4_ROW + h * 128;
            xr[s][0] = xv[xo + lane];
            xr[s][1] = xv[xo + 64 + lane];
        }

        const float4* cb = reinterpret_cast<const float4*>(centers)
                         + (size_t)cls * (K_SUB * F4_ROW) + h * 128 + lane;

        const bool b0 = (lane & 1) != 0;
        const bool b1 = (lane & 2) != 0;
        const bool b2 = (lane & 4) != 0;
        const bool b3 = (lane & 8) != 0;
        const int kmap = 8 * (lane & 1) + 4 * ((lane >> 1) & 1)
                       + 2 * ((lane >> 2) & 1) + ((lane >> 3) & 1);

#define REDUCE16(A, OUT)                                                      \
    {                                                                         \
        _Pragma("unroll")                                                     \
        for (int jj = 0; jj < 8; ++jj) {                                      \
            const float send = b0 ? A[jj] : A[jj + 8];                        \
            const float recv = dpp_qperm<0xB1>(send);       /* xor 1 */       \
            A[jj] = (b0 ? A[jj + 8] : A[jj]) + recv;                          \
        }                                                                     \
        _Pragma("unroll")                                                     \
        for (int jj = 0; jj < 4; ++jj) {                                      \
            const float send = b1 ? A[jj] : A[jj + 4];                        \
            const float recv = dpp_qperm<0x4E>(send);       /* xor 2 */       \
            A[jj] = (b1 ? A[jj + 4] : A[jj]) + recv;                          \
        }                                                                     \
        _Pragma("unroll")                                                     \
        for (int jj = 0; jj < 2; ++jj) {                                      \
            const float send = b2 ? A[jj] : A[jj + 2];                        \
            const float recv = __shfl_xor(send, 4, 64);                       \
            A[jj] = (b2 ? A[jj + 2] : A[jj]) + recv;                          \
        }                                                                     \
        {                                                                     \
            const float send = b3 ? A[0] : A[1];                              \
            const float recv = __shfl_xor(send, 8, 64);                       \
            A[0] = (b3 ? A[1] : A[0]) + recv;                                 \
        }                                                                     \
        A[0] += __shfl_xor(A[0], 16, 64);                                     \
        A[0] += __shfl_xor(A[0], 32, 64);                                     \
        OUT = A[0];                                                           \
    }

        // 4 k-groups: only 16 accumulators live at a time (low VGPR).
#pragma unroll
        for (int kq = 0; kq < 4; ++kq) {
            float A[16];
#pragma unroll
            for (int kk = 0; kk < 4; ++kk) {
                const int k = kq * 4 + kk;
                const float4 q0 = cb[k * F4_ROW];
                const float4 q1 = cb[k * F4_ROW + 64];
                A[0 * 4 + kk] = dot8(q0, q1, xr[0][0], xr[0][1]);
                A[1 * 4 + kk] = dot8(q0, q1, xr[1][0], xr[1][1]);
                A[2 * 4 + kk] = dot8(q0, q1, xr[2][0], xr[2][1]);
                A[3 * 4 + kk] = dot8(q0, q1, xr[3][0], xr[3][1]);
            }
            float r;
            REDUCE16(A, r)
            // A[v] with v = s*4+kk  ->  lane holds v = kmap
            if (lane < 16) sdots[wv][kmap >> 2][kq * 4 + (kmap & 3)] = r;
        }
#undef REDUCE16

        if (h == 0 && lane < 4)
            sgate[pair][lane] = (base + lane < cntc) ? 1.0f : 0.0f;
    } else {
        // dead pair: zero its sdots half + gates, then join the barrier
        if (lane < 16) {
#pragma unroll
            for (int s = 0; s < 4; ++s) sdots[wv][s][lane] = 0.0f;
        }
        if (h == 0 && lane < 4) sgate[pair][lane] = 0.0f;
    }

    __syncthreads();

    // epilogue: wave 0 -> pair 0, wave 1 -> pair 1
    if (wv < 2) {
        const int s  = lane >> 4;
        const int kk = lane & 15;
        const float r = sdots[wv * 2][s][kk] + sdots[wv * 2 + 1][s][kk];
        float wl = sample_loss16(r, kk) * sgate[wv][s];
        wl += __shfl_xor(wl, 16, 64);
        wl += __shfl_xor(wl, 32, 64);
        if (lane == 0) partials[b * 2 + wv] = wl;
    }
}

// ---------------- Kernel 3: final mean over NPART partials ----------------
__global__ __launch_bounds__(256) void reduce_final(
    const float* __restrict__ partials,
    float*       __restrict__ out)
{
    const int tid  = threadIdx.x;
    const int wave = tid >> 6;
    const int lane = tid & 63;
    float s = 0.0f;
    for (int i = tid; i < NPART; i += 256) s += partials[i];
#pragma unroll
    for (int off = 32; off > 0; off >>= 1) s += __shfl_xor(s, off, 64);
    __shared__ float w[4];
    if (lane == 0) w[wave] = s;
    __syncthreads();
    if (tid == 0)
        out[0] = (w[0] + w[1] + w[2] + w[3]) * (1.0f / (float)B_SAMP);
}

extern "C" void kernel_launch(void* const* d_in, const int* in_sizes, int n_in,
                              void* d_out, int out_size, void* d_ws, size_t ws_size,
                              hipStream_t stream)
{
    const float* x       = (const float*)d_in[0];
    const int*   labels  = (const int*)  d_in[1];
    const float* centers = (const float*)d_in[2];
    float*       out     = (float*)d_out;
    char*        ws      = (char*)d_ws;

    int*   counts = (int*)  (ws + OFF_COUNTS);
    int*   lists  = (int*)  (ws + OFF_LISTS);
    float* parts  = (float*)(ws + OFF_PART);

    bin_labels  <<<C_CLS, 256, 0, stream>>>(labels, counts, lists);
    quad_dots   <<<NBLK,  256, 0, stream>>>(x, centers, counts, lists, parts);
    reduce_final<<<1,     256, 0, stream>>>(parts, out);
}